// Round 3
// baseline (465.367 us; speedup 1.0000x reference)
//
#include <hip/hip_runtime.h>

typedef __attribute__((ext_vector_type(8))) short short8;
typedef __attribute__((ext_vector_type(4))) short short4v;
typedef __attribute__((ext_vector_type(4))) float floatx4;

#define NWSIDE 14
#define HLEN   56
#define DM     256

// LDS layout (bf16 element offsets). Total 27136 elems = 54,272 B -> 3 blocks/CU.
#define QK_STRIDE 264                  // 16 tokens x 264 (8-elem pad: b128-aligned, conflict-spread)
#define Q_OFF  0                       // [2][16][264]
#define K_OFF  8448                    // [2][16][264]
#define VT_OFF 16896                   // [2][256 e][16 s]  (V transposed)
#define P_OFF  25088                   // [4 waves][16 t][32 s] (cols 16..31 stay zero)
#define LDS_TOT 27136

static __device__ __forceinline__ unsigned short f2bf(float f) {
    unsigned int u = __float_as_uint(f);
    unsigned int r = (u + 0x7fffu + ((u >> 16) & 1u)) >> 16;   // RNE
    return (unsigned short)r;
}

// ---- prep: coalesced read of W fp32 [256 k][768 c]; scatter bf16 into Wt[col'][k] ----
// col' = h*96 + sect*32 + e   <-   c = h*96 + e*3 + sect
__global__ void swin_prep(const float* __restrict__ W, const float* __restrict__ bias,
                          unsigned short* __restrict__ Wt, float* __restrict__ bperm) {
    int gid = blockIdx.x * 256 + threadIdx.x;    // 0..196607, gid = k*768 + c
    int k = gid / 768;
    int c = gid - k * 768;
    float wv = W[gid];
    int h = c / 96;
    int rr = c - h * 96;
    int e = rr / 3;
    int sect = rr - e * 3;
    int cp = h * 96 + sect * 32 + e;
    Wt[cp * 256 + k] = f2bf(wv);
    if (gid < 768) bperm[cp] = bias[c];          // k==0 rows carry the bias
}

// 1568 blocks (32 b x 49 window-groups) x 256 threads (4 waves).
// Per block: 4 windows, processed in 2 LDS passes of 2 windows each.
__global__ __launch_bounds__(256, 3)
void swin_mfma(const float* __restrict__ x,
               const unsigned short* __restrict__ Wt,
               const float* __restrict__ bperm,
               float* __restrict__ out) {
    __shared__ unsigned short lds[LDS_TOT];

    const int blk = blockIdx.x;
    const int b   = blk / 49;
    const int g   = blk % 49;
    const int tid = threadIdx.x;
    const int wv  = tid >> 6;
    const int lane = tid & 63;
    const int lrow = lane & 15;
    const int lq   = lane >> 4;
    const float scale = 0.17677669529663687f;    // 1/sqrt(32)
    const floatx4 zf = {0.f, 0.f, 0.f, 0.f};

    // zero the k>=16 half of this wave's P scratch (A-side zeros for the padded-K PV MFMA)
    {
        short4v z = {};
        int row = lane >> 2, col = 16 + (lane & 3) * 4;
        *(short4v*)&lds[P_OFF + wv * 512 + row * 32 + col] = z;
    }

    const int u_att  = wv >> 1;          // attention window (within pass) for this wave
    const int hbase  = (wv & 1) * 4;     // attention heads hbase..hbase+3

    short8 A[2][8];
    // ---- load A fragments for pass-0 windows ----
    #pragma unroll
    for (int u = 0; u < 2; ++u) {
        const int ww = g * 4 + u;
        const int wi = ww / NWSIDE, wj = ww % NWSIDE;
        const int gr = (wi * 4 + (lrow >> 2) + 2) % HLEN;
        const int gc = (wj * 4 + (lrow & 3) + 2) % HLEN;
        const float* xp = x + ((size_t)(b * 3136 + gr * 56 + gc)) * DM + lq * 8;
        #pragma unroll
        for (int ks = 0; ks < 8; ++ks) {
            floatx4 f0 = *(const floatx4*)(xp + ks * 32);
            floatx4 f1 = *(const floatx4*)(xp + ks * 32 + 4);
            short8 a;
            a[0] = (short)f2bf(f0[0]); a[1] = (short)f2bf(f0[1]);
            a[2] = (short)f2bf(f0[2]); a[3] = (short)f2bf(f0[3]);
            a[4] = (short)f2bf(f1[0]); a[5] = (short)f2bf(f1[1]);
            a[6] = (short)f2bf(f1[2]); a[7] = (short)f2bf(f1[3]);
            A[u][ks] = a;
        }
    }

    #pragma unroll
    for (int pass = 0; pass < 2; ++pass) {
        if (pass) __syncthreads();   // previous attention done before overwriting LDS

        // ---------------- GEMM: wave wv owns n-tiles [12wv,12wv+12), both windows ----------------
        #pragma unroll
        for (int n = 0; n < 12; ++n) {
            const int t    = wv * 12 + n;
            const int col0 = t * 16;
            const int h    = t / 6;
            const int r    = col0 - h * 96;
            const int sect = r >> 5;
            const int e0   = r & 31;
            const float bv = bperm[col0 + lrow];
            floatx4 acc[2];
            acc[0][0] = bv; acc[0][1] = bv; acc[0][2] = bv; acc[0][3] = bv;
            acc[1] = acc[0];
            const unsigned short* wp = Wt + (size_t)(col0 + lrow) * 256 + lq * 8;
            #pragma unroll
            for (int ks = 0; ks < 8; ++ks) {
                short8 Bf = *(const short8*)(wp + ks * 32);
                acc[0] = __builtin_amdgcn_mfma_f32_16x16x32_bf16(A[0][ks], Bf, acc[0], 0, 0, 0);
                acc[1] = __builtin_amdgcn_mfma_f32_16x16x32_bf16(A[1][ks], Bf, acc[1], 0, 0, 0);
            }
            const int cfull = h * 32 + e0 + lrow;    // column within q/k/vT arrays
            if (sect == 2) {
                #pragma unroll
                for (int u = 0; u < 2; ++u) {
                    short4v pv;
                    pv[0] = (short)f2bf(acc[u][0]); pv[1] = (short)f2bf(acc[u][1]);
                    pv[2] = (short)f2bf(acc[u][2]); pv[3] = (short)f2bf(acc[u][3]);
                    *(short4v*)&lds[VT_OFF + u * 4096 + cfull * 16 + lq * 4] = pv;
                }
            } else {
                const int abase = (sect == 0 ? Q_OFF : K_OFF);
                #pragma unroll
                for (int u = 0; u < 2; ++u)
                    #pragma unroll
                    for (int i = 0; i < 4; ++i)
                        lds[abase + u * 4224 + (lq * 4 + i) * QK_STRIDE + cfull] = f2bf(acc[u][i]);
            }
        }

        // prefetch A for pass 1 while pass-0 attention runs
        if (pass == 0) {
            #pragma unroll
            for (int u = 0; u < 2; ++u) {
                const int ww = g * 4 + 2 + u;
                const int wi = ww / NWSIDE, wj = ww % NWSIDE;
                const int gr = (wi * 4 + (lrow >> 2) + 2) % HLEN;
                const int gc = (wj * 4 + (lrow & 3) + 2) % HLEN;
                const float* xp = x + ((size_t)(b * 3136 + gr * 56 + gc)) * DM + lq * 8;
                #pragma unroll
                for (int ks = 0; ks < 8; ++ks) {
                    floatx4 f0 = *(const floatx4*)(xp + ks * 32);
                    floatx4 f1 = *(const floatx4*)(xp + ks * 32 + 4);
                    short8 a;
                    a[0] = (short)f2bf(f0[0]); a[1] = (short)f2bf(f0[1]);
                    a[2] = (short)f2bf(f0[2]); a[3] = (short)f2bf(f0[3]);
                    a[4] = (short)f2bf(f1[0]); a[5] = (short)f2bf(f1[1]);
                    a[6] = (short)f2bf(f1[2]); a[7] = (short)f2bf(f1[3]);
                    A[u][ks] = a;
                }
            }
        }
        __syncthreads();   // qkv tiles visible

        // ---------------- attention: wave wv -> window u_att, heads hbase..hbase+3 ----------------
        {
            const int ww = g * 4 + pass * 2 + u_att;
            const int wi = ww / NWSIDE, wj = ww % NWSIDE;
            const bool lastrow = (wi == NWSIDE - 1);
            const bool lastcol = (wj == NWSIDE - 1);
            // output row bases: token t = lq*4+i -> gr depends on lq only, gc on i only
            const int gr = (wi * 4 + lq + 2) % HLEN;
            int rowbase[4];
            #pragma unroll
            for (int i = 0; i < 4; ++i) {
                const int gc = (wj * 4 + i + 2) % HLEN;
                rowbase[i] = (b * 3136 + gr * 56 + gc) * DM;
            }
            const bool t_hi = (lq >= 2);            // token >= 8
            const bool s_hi = (lrow >= 8);
            const bool s_c2 = ((lrow & 3) >= 2);

            #pragma unroll
            for (int hh = 0; hh < 4; ++hh) {
                const int h = hbase + hh;
                const int qkc = h * 32 + lq * 8;
                short8 Aq = *(short8*)&lds[Q_OFF + u_att * 4224 + lrow * QK_STRIDE + qkc];
                short8 Bk = *(short8*)&lds[K_OFF + u_att * 4224 + lrow * QK_STRIDE + qkc];
                floatx4 S = __builtin_amdgcn_mfma_f32_16x16x32_bf16(Aq, Bk, zf, 0, 0, 0);

                #pragma unroll
                for (int i = 0; i < 4; ++i) {
                    float sv = S[i] * scale;
                    if (lastrow && (t_hi != s_hi)) sv = -1e30f;
                    if (lastcol && ((i >= 2) != s_c2)) sv = -1e30f;
                    float m = sv;
                    m = fmaxf(m, __shfl_xor(m, 1));
                    m = fmaxf(m, __shfl_xor(m, 2));
                    m = fmaxf(m, __shfl_xor(m, 4));
                    m = fmaxf(m, __shfl_xor(m, 8));
                    float ev = __expf(sv - m);
                    float s2 = ev;
                    s2 += __shfl_xor(s2, 1);
                    s2 += __shfl_xor(s2, 2);
                    s2 += __shfl_xor(s2, 4);
                    s2 += __shfl_xor(s2, 8);
                    float p = ev / s2;
                    lds[P_OFF + wv * 512 + (lq * 4 + i) * 32 + lrow] = f2bf(p);
                }
                // read P as A-fragment (k = lq*8+j; j>=16 region is zero)
                short8 Ap = *(short8*)&lds[P_OFF + wv * 512 + lrow * 32 + lq * 8];
                #pragma unroll
                for (int eb = 0; eb < 2; ++eb) {
                    // B[k=s][n=e] = vT[e][s]; lanes lq>=2 hit A-zeros, re-read finite data
                    short8 Bv = *(short8*)&lds[VT_OFF + u_att * 4096 +
                                               (h * 32 + eb * 16 + lrow) * 16 + (lq & 1) * 8];
                    floatx4 O = __builtin_amdgcn_mfma_f32_16x16x32_bf16(Ap, Bv, zf, 0, 0, 0);
                    #pragma unroll
                    for (int i = 0; i < 4; ++i)
                        out[rowbase[i] + h * 32 + eb * 16 + lrow] = O[i];
                }
            }
        }
    }
}

extern "C" void kernel_launch(void* const* d_in, const int* in_sizes, int n_in,
                              void* d_out, int out_size, void* d_ws, size_t ws_size,
                              hipStream_t stream) {
    const float* x    = (const float*)d_in[0];
    const float* W    = (const float*)d_in[1];
    const float* bias = (const float*)d_in[2];
    float* out = (float*)d_out;
    (void)in_sizes; (void)n_in; (void)out_size; (void)ws_size;

    unsigned short* Wt = (unsigned short*)d_ws;                // 768*256*2 = 393216 B
    float* bperm = (float*)((char*)d_ws + 768 * 256 * 2);      // +3072 B

    swin_prep<<<768, 256, 0, stream>>>(W, bias, Wt, bperm);
    swin_mfma<<<32 * 49, 256, 0, stream>>>(x, Wt, bperm, out);
}

// Round 4
// 357.305 us; speedup vs baseline: 1.3024x; 1.3024x over previous
//
#include <hip/hip_runtime.h>

typedef __attribute__((ext_vector_type(8))) short short8;
typedef __attribute__((ext_vector_type(4))) short short4v;
typedef __attribute__((ext_vector_type(4))) float floatx4;

#define NWSIDE 14
#define HLEN   56
#define DM     256

// Per-window LDS (bf16 elems): Q[16][264] + K[16][264] + VT[256][16]
#define QK_STRIDE 264
#define K_OFF     4224
#define VT_OFF    8448
#define WINELEMS  12544          // x2 windows = 25088 elems = 50176 B -> 3 blocks/CU

static __device__ __forceinline__ unsigned int f2bfu(float f) {
    unsigned int u = __float_as_uint(f);
    return (u + 0x7fffu + ((u >> 16) & 1u)) >> 16;    // RNE
}
static __device__ __forceinline__ unsigned short f2bf(float f) {
    return (unsigned short)f2bfu(f);
}

// prep: Wt[col'][k] bf16, col' = h*96 + sect*32 + e  <-  c = h*96 + e*3 + sect
// coalesced 2B stores (consecutive threads share col', walk k)
__global__ void swin_prep(const float* __restrict__ W, const float* __restrict__ bias,
                          unsigned short* __restrict__ Wt, float* __restrict__ bperm) {
    int idx = blockIdx.x * 256 + threadIdx.x;   // 0..196607
    int cp = idx >> 8, k = idx & 255;
    int h = cp / 96, r = cp % 96;
    int sect = r >> 5, e = r & 31;
    int c = h * 96 + e * 3 + sect;
    Wt[idx] = f2bf(W[(size_t)k * 768 + c]);
    if (k == 0) bperm[cp] = bias[c];
}

// 3136 blocks (32 b x 98 pairs) x 256 threads (4 waves). 2 windows/block, ONE barrier.
__global__ __launch_bounds__(256, 3)
void swin_mfma(const float* __restrict__ x,
               const unsigned short* __restrict__ Wt,
               const float* __restrict__ bperm,
               float* __restrict__ out) {
    __shared__ unsigned short lds[2 * WINELEMS];

    const int b    = blockIdx.x / 98;
    const int g    = blockIdx.x % 98;           // windows 2g, 2g+1
    const int tid  = threadIdx.x;
    const int wv   = tid >> 6;
    const int lane = tid & 63;
    const int lrow = lane & 15;
    const int lq   = lane >> 4;
    const float scale = 0.17677669529663687f;   // 1/sqrt(32)
    const floatx4 zf = {0.f, 0.f, 0.f, 0.f};

    // ---- x fragments (MFMA B-operand: B[k=lq*8+j][tok=lrow]) for both windows ----
    short8 xf[2][8];
    #pragma unroll
    for (int u = 0; u < 2; ++u) {
        const int ww = g * 2 + u;
        const int wi = ww / NWSIDE, wj = ww % NWSIDE;
        const int gr = (wi * 4 + (lrow >> 2) + 2) % HLEN;
        const int gc = (wj * 4 + (lrow & 3) + 2) % HLEN;
        const float* xp = x + ((size_t)(b * 3136 + gr * 56 + gc)) * DM + lq * 8;
        #pragma unroll
        for (int ks = 0; ks < 8; ++ks) {
            floatx4 f0 = *(const floatx4*)(xp + ks * 32);
            floatx4 f1 = *(const floatx4*)(xp + ks * 32 + 4);
            short8 a;
            a[0] = (short)f2bf(f0[0]); a[1] = (short)f2bf(f0[1]);
            a[2] = (short)f2bf(f0[2]); a[3] = (short)f2bf(f0[3]);
            a[4] = (short)f2bf(f1[0]); a[5] = (short)f2bf(f1[1]);
            a[6] = (short)f2bf(f1[2]); a[7] = (short)f2bf(f1[3]);
            xf[u][ks] = a;
        }
    }

    // ---- GEMM: qkv^T tiles; wave wv owns n-tiles [12wv, 12wv+12) ----
    #pragma unroll
    for (int n = 0; n < 12; ++n) {
        const int t    = wv * 12 + n;
        const int col0 = t * 16;
        const int h    = t / 6;
        const int r    = col0 - h * 96;
        const int sect = r >> 5;
        const int e0   = r & 31;
        floatx4 bv = *(const floatx4*)&bperm[col0 + lq * 4];
        floatx4 acc0 = bv, acc1 = bv;
        const unsigned short* wp = Wt + (size_t)(col0 + lrow) * 256 + lq * 8;
        #pragma unroll
        for (int ks = 0; ks < 8; ++ks) {
            short8 Af = *(const short8*)(wp + ks * 32);   // A[m=col][k]
            acc0 = __builtin_amdgcn_mfma_f32_16x16x32_bf16(Af, xf[0][ks], acc0, 0, 0, 0);
            acc1 = __builtin_amdgcn_mfma_f32_16x16x32_bf16(Af, xf[1][ks], acc1, 0, 0, 0);
        }
        // lane holds qkv[tok=lrow][col0 + lq*4 + i]
        if (sect < 2) {
            const int base = (sect ? K_OFF : 0) + lrow * QK_STRIDE + h * 32 + e0 + lq * 4;
            short4v p0, p1;
            p0[0] = (short)f2bf(acc0[0]); p0[1] = (short)f2bf(acc0[1]);
            p0[2] = (short)f2bf(acc0[2]); p0[3] = (short)f2bf(acc0[3]);
            p1[0] = (short)f2bf(acc1[0]); p1[1] = (short)f2bf(acc1[1]);
            p1[2] = (short)f2bf(acc1[2]); p1[3] = (short)f2bf(acc1[3]);
            *(short4v*)&lds[base]            = p0;
            *(short4v*)&lds[WINELEMS + base] = p1;
        } else {
            #pragma unroll
            for (int i = 0; i < 4; ++i) {
                const int rowe = h * 32 + e0 + lq * 4 + i;
                lds[VT_OFF + rowe * 16 + lrow]            = f2bf(acc0[i]);
                lds[WINELEMS + VT_OFF + rowe * 16 + lrow] = f2bf(acc1[i]);
            }
        }
    }
    __syncthreads();

    // ---- attention: wave wv -> window wv>>1, heads (wv&1)*4.. ----
    const int u     = wv >> 1;
    const int hbase = (wv & 1) * 4;
    const int ww = g * 2 + u;
    const int wi = ww / NWSIDE, wj = ww % NWSIDE;
    const bool lastrow = (wi == NWSIDE - 1);
    const bool lastcol = (wj == NWSIDE - 1);
    const int gr = (wi * 4 + (lrow >> 2) + 2) % HLEN;
    const int gc = (wj * 4 + (lrow & 3) + 2) % HLEN;
    float* orow = out + ((size_t)(b * 3136 + gr * 56 + gc)) * DM;   // token t=lrow
    const unsigned short* wl = lds + u * WINELEMS;
    const bool mrow = lastrow && ((lrow >= 8) != (lq >= 2));        // whole-lane
    const bool mc   = ((lrow & 3) >= 2);                            // t&3 >= 2
    const int vtq = (lq & 1) * 8;

    #pragma unroll
    for (int hh = 0; hh < 4; ++hh) {
        const int h = hbase + hh;
        short8 Ak = *(const short8*)&wl[K_OFF + lrow * QK_STRIDE + h * 32 + lq * 8];
        short8 Bq = *(const short8*)&wl[lrow * QK_STRIDE + h * 32 + lq * 8];
        floatx4 ST = __builtin_amdgcn_mfma_f32_16x16x32_bf16(Ak, Bq, zf, 0, 0, 0);
        // lane holds S^T[s = lq*4+i][t = lrow]
        float ev[4];
        #pragma unroll
        for (int i = 0; i < 4; ++i) {
            bool m = mrow || (lastcol && (mc != (i >= 2)));
            ev[i] = __expf(m ? -1e30f : ST[i] * scale);
        }
        float rs = (ev[0] + ev[1]) + (ev[2] + ev[3]);
        rs += __shfl_xor(rs, 16);
        rs += __shfl_xor(rs, 32);
        const float inv = 1.0f / rs;
        const unsigned int d0 = f2bfu(ev[0] * inv) | (f2bfu(ev[1] * inv) << 16);
        const unsigned int d1 = f2bfu(ev[2] * inv) | (f2bfu(ev[3] * inv) << 16);
        // build P^T B-fragment: lane needs s = lq*8 + j (j 0..7); zero for lq>=2
        const int src0 = lrow + ((lq & 1) << 5);
        int b0 = __shfl((int)d0, src0);
        int b1 = __shfl((int)d1, src0);
        int b2 = __shfl((int)d0, src0 + 16);
        int b3 = __shfl((int)d1, src0 + 16);
        if (lq >= 2) { b0 = 0; b1 = 0; b2 = 0; b3 = 0; }
        union { int i4[4]; short8 s8; } bp;
        bp.i4[0] = b0; bp.i4[1] = b1; bp.i4[2] = b2; bp.i4[3] = b3;
        #pragma unroll
        for (int eb = 0; eb < 2; ++eb) {
            short8 Av = *(const short8*)&wl[VT_OFF + (h * 32 + eb * 16 + lrow) * 16 + vtq];
            floatx4 O = __builtin_amdgcn_mfma_f32_16x16x32_bf16(Av, bp.s8, zf, 0, 0, 0);
            // lane holds O[t=lrow][e = eb*16 + lq*4 + i] -> contiguous float4
            *(floatx4*)&orow[h * 32 + eb * 16 + lq * 4] = O;
        }
    }
}

extern "C" void kernel_launch(void* const* d_in, const int* in_sizes, int n_in,
                              void* d_out, int out_size, void* d_ws, size_t ws_size,
                              hipStream_t stream) {
    const float* x    = (const float*)d_in[0];
    const float* W    = (const float*)d_in[1];
    const float* bias = (const float*)d_in[2];
    float* out = (float*)d_out;
    (void)in_sizes; (void)n_in; (void)out_size; (void)ws_size;

    unsigned short* Wt = (unsigned short*)d_ws;                // 393216 B
    float* bperm = (float*)((char*)d_ws + 768 * 256 * 2);      // +3072 B

    swin_prep<<<768, 256, 0, stream>>>(W, bias, Wt, bperm);
    swin_mfma<<<32 * 98, 256, 0, stream>>>(x, Wt, bperm, out);
}

// Round 5
// 326.980 us; speedup vs baseline: 1.4232x; 1.0927x over previous
//
#include <hip/hip_runtime.h>

typedef __attribute__((ext_vector_type(8))) short short8;
typedef __attribute__((ext_vector_type(4))) short short4v;
typedef __attribute__((ext_vector_type(4))) float floatx4;

#define NWSIDE 14
#define HLEN   56
#define DM     256

// Per-window LDS (bf16 elems): Q[16][264] @0, K[16][264] @4224, VT[256][16] @8448
// xs (staged x, bf16) overlays the Q region; O (fp32) overlays Q+K after attention reads.
#define QK_STRIDE 264
#define K_OFF     4224
#define VT_OFF    8448
#define WINELEMS  12544          // x2 windows = 25088 elems = 50176 B -> 3 blocks/CU
#define OW_F      6272           // fp32 stride per window for O staging (25088B/4)

static __device__ __forceinline__ unsigned int f2bfu(float f) {
    unsigned int u = __float_as_uint(f);
    return (u + 0x7fffu + ((u >> 16) & 1u)) >> 16;    // RNE
}
static __device__ __forceinline__ unsigned short f2bf(float f) {
    return (unsigned short)f2bfu(f);
}

// prep: Wt[col'][k] bf16, col' = h*96 + sect*32 + e  <-  c = h*96 + e*3 + sect
__global__ void swin_prep(const float* __restrict__ W, const float* __restrict__ bias,
                          unsigned short* __restrict__ Wt, float* __restrict__ bperm) {
    int idx = blockIdx.x * 256 + threadIdx.x;   // 0..196607
    int cp = idx >> 8, k = idx & 255;
    int h = cp / 96, r = cp % 96;
    int sect = r >> 5, e = r & 31;
    int c = h * 96 + e * 3 + sect;
    Wt[idx] = f2bf(W[(size_t)k * 768 + c]);
    if (k == 0) bperm[cp] = bias[c];
}

// 3136 blocks (32 b x 98 pairs) x 256 threads (4 waves). 2 windows/block.
__global__ __launch_bounds__(256, 3)
void swin_mfma(const float* __restrict__ x,
               const unsigned short* __restrict__ Wt,
               const float* __restrict__ bperm,
               float* __restrict__ out) {
    __shared__ __align__(16) unsigned short lds[2 * WINELEMS];

    const int b    = blockIdx.x / 98;
    const int g    = blockIdx.x % 98;           // windows 2g, 2g+1
    const int tid  = threadIdx.x;
    const int wv   = tid >> 6;
    const int lane = tid & 63;
    const int lrow = lane & 15;
    const int lq   = lane >> 4;
    const float scale = 0.17677669529663687f;   // 1/sqrt(32)
    const floatx4 zf = {0.f, 0.f, 0.f, 0.f};

    // cooperative-phase mapping: thread -> (window u2, token tk, segment sg)
    const int u2 = tid >> 7, tk = (tid >> 3) & 15, sg = tid & 7;
    const int ww2 = g * 2 + u2;
    const int wi2 = ww2 / NWSIDE, wj2 = ww2 % NWSIDE;
    const int gr2 = (wi2 * 4 + (tk >> 2) + 2) % HLEN;
    const int gc2 = (wj2 * 4 + (tk & 3) + 2) % HLEN;
    const size_t rowoff = ((size_t)(b * 3136 + gr2 * 56 + gc2)) * DM;

    // ---- phase 1: cooperative x load (contiguous 1KB token rows) -> bf16 LDS ----
    {
        const floatx4* xr = (const floatx4*)(x + rowoff);
        unsigned short* xd = &lds[u2 * WINELEMS + tk * QK_STRIDE];
        #pragma unroll
        for (int j = 0; j < 8; ++j) {
            floatx4 f = xr[sg + 8 * j];          // 128B contiguous per 8 lanes
            short4v p;
            p[0] = (short)f2bf(f[0]); p[1] = (short)f2bf(f[1]);
            p[2] = (short)f2bf(f[2]); p[3] = (short)f2bf(f[3]);
            *(short4v*)&xd[(sg + 8 * j) * 4] = p;
        }
    }
    __syncthreads();

    // ---- phase 2: build MFMA B-fragments from LDS (conflict-free b128) ----
    short8 xf[2][8];
    #pragma unroll
    for (int u = 0; u < 2; ++u)
        #pragma unroll
        for (int ks = 0; ks < 8; ++ks)
            xf[u][ks] = *(const short8*)&lds[u * WINELEMS + lrow * QK_STRIDE + ks * 32 + lq * 8];
    __syncthreads();   // xs dead; Q region reusable

    // ---- phase 3: GEMM qkv^T; wave wv owns n-tiles [12wv, 12wv+12) ----
    #pragma unroll
    for (int n = 0; n < 12; ++n) {
        const int t    = wv * 12 + n;
        const int col0 = t * 16;
        const int h    = t / 6;
        const int r    = col0 - h * 96;
        const int sect = r >> 5;
        const int e0   = r & 31;
        floatx4 bv = *(const floatx4*)&bperm[col0 + lq * 4];
        floatx4 acc0 = bv, acc1 = bv;
        const unsigned short* wp = Wt + (size_t)(col0 + lrow) * 256 + lq * 8;
        #pragma unroll
        for (int ks = 0; ks < 8; ++ks) {
            short8 Af = *(const short8*)(wp + ks * 32);   // A[m=col][k], L2-hot
            acc0 = __builtin_amdgcn_mfma_f32_16x16x32_bf16(Af, xf[0][ks], acc0, 0, 0, 0);
            acc1 = __builtin_amdgcn_mfma_f32_16x16x32_bf16(Af, xf[1][ks], acc1, 0, 0, 0);
        }
        // lane holds qkv[tok=lrow][col0 + lq*4 + i]
        if (sect < 2) {
            const int base = (sect ? K_OFF : 0) + lrow * QK_STRIDE + h * 32 + e0 + lq * 4;
            short4v p0, p1;
            p0[0] = (short)f2bf(acc0[0]); p0[1] = (short)f2bf(acc0[1]);
            p0[2] = (short)f2bf(acc0[2]); p0[3] = (short)f2bf(acc0[3]);
            p1[0] = (short)f2bf(acc1[0]); p1[1] = (short)f2bf(acc1[1]);
            p1[2] = (short)f2bf(acc1[2]); p1[3] = (short)f2bf(acc1[3]);
            *(short4v*)&lds[base]            = p0;
            *(short4v*)&lds[WINELEMS + base] = p1;
        } else {
            #pragma unroll
            for (int i = 0; i < 4; ++i) {
                const int rowe = h * 32 + e0 + lq * 4 + i;
                lds[VT_OFF + rowe * 16 + lrow]            = f2bf(acc0[i]);
                lds[WINELEMS + VT_OFF + rowe * 16 + lrow] = f2bf(acc1[i]);
            }
        }
    }
    __syncthreads();

    // ---- phase 4: S^T precompute (all Q/K reads happen here) ----
    const int u     = wv >> 1;
    const int hbase = (wv & 1) * 4;
    const int ww = g * 2 + u;
    const int wi = ww / NWSIDE, wj = ww % NWSIDE;
    const bool lastrow = (wi == NWSIDE - 1);
    const bool lastcol = (wj == NWSIDE - 1);
    const unsigned short* wl = lds + u * WINELEMS;
    const bool mrow = lastrow && ((lrow >= 8) != (lq >= 2));
    const bool mc   = ((lrow & 3) >= 2);
    const int vtq = (lq & 1) * 8;

    floatx4 ST[4];
    #pragma unroll
    for (int hh = 0; hh < 4; ++hh) {
        const int h = hbase + hh;
        short8 Ak = *(const short8*)&wl[K_OFF + lrow * QK_STRIDE + h * 32 + lq * 8];
        short8 Bq = *(const short8*)&wl[lrow * QK_STRIDE + h * 32 + lq * 8];
        ST[hh] = __builtin_amdgcn_mfma_f32_16x16x32_bf16(Ak, Bq, zf, 0, 0, 0);
    }
    __syncthreads();   // Q/K dead; O staging may overwrite

    // ---- phase 5: softmax + PV, O -> LDS (fp32, over old Q+K region) ----
    float* Of = (float*)lds;
    #pragma unroll
    for (int hh = 0; hh < 4; ++hh) {
        const int h = hbase + hh;
        // lane holds S^T[s = lq*4+i][t = lrow]
        float ev[4];
        #pragma unroll
        for (int i = 0; i < 4; ++i) {
            bool m = mrow || (lastcol && (mc != (i >= 2)));
            ev[i] = __expf(m ? -1e30f : ST[hh][i] * scale);
        }
        float rs = (ev[0] + ev[1]) + (ev[2] + ev[3]);
        rs += __shfl_xor(rs, 16);
        rs += __shfl_xor(rs, 32);
        const float inv = 1.0f / rs;
        const unsigned int d0 = f2bfu(ev[0] * inv) | (f2bfu(ev[1] * inv) << 16);
        const unsigned int d1 = f2bfu(ev[2] * inv) | (f2bfu(ev[3] * inv) << 16);
        // P^T B-fragment: lane needs s = lq*8 + j (j 0..7); zero for lq>=2
        const int src0 = lrow + ((lq & 1) << 5);
        int b0 = __shfl((int)d0, src0);
        int b1 = __shfl((int)d1, src0);
        int b2 = __shfl((int)d0, src0 + 16);
        int b3 = __shfl((int)d1, src0 + 16);
        if (lq >= 2) { b0 = 0; b1 = 0; b2 = 0; b3 = 0; }
        union { int i4[4]; short8 s8; } bp;
        bp.i4[0] = b0; bp.i4[1] = b1; bp.i4[2] = b2; bp.i4[3] = b3;
        #pragma unroll
        for (int eb = 0; eb < 2; ++eb) {
            short8 Av = *(const short8*)&wl[VT_OFF + (h * 32 + eb * 16 + lrow) * 16 + vtq];
            floatx4 O = __builtin_amdgcn_mfma_f32_16x16x32_bf16(Av, bp.s8, zf, 0, 0, 0);
            // lane holds O[t=lrow][e = eb*16 + lq*4 + i]
            *(floatx4*)&Of[u * OW_F + lrow * QK_STRIDE + h * 32 + eb * 16 + lq * 4] = O;
        }
    }
    __syncthreads();

    // ---- phase 6: cooperative store (contiguous 1KB token rows) ----
    {
        float* op = out + rowoff;
        const float* Os = &Of[u2 * OW_F + tk * QK_STRIDE];
        #pragma unroll
        for (int j = 0; j < 8; ++j)
            *(floatx4*)&op[(sg + 8 * j) * 4] = *(const floatx4*)&Os[(sg + 8 * j) * 4];
    }
}

extern "C" void kernel_launch(void* const* d_in, const int* in_sizes, int n_in,
                              void* d_out, int out_size, void* d_ws, size_t ws_size,
                              hipStream_t stream) {
    const float* x    = (const float*)d_in[0];
    const float* W    = (const float*)d_in[1];
    const float* bias = (const float*)d_in[2];
    float* out = (float*)d_out;
    (void)in_sizes; (void)n_in; (void)out_size; (void)ws_size;

    unsigned short* Wt = (unsigned short*)d_ws;                // 393216 B
    float* bperm = (float*)((char*)d_ws + 768 * 256 * 2);      // +3072 B

    swin_prep<<<768, 256, 0, stream>>>(W, bias, Wt, bperm);
    swin_mfma<<<32 * 98, 256, 0, stream>>>(x, Wt, bperm, out);
}